// Round 21
// baseline (271.501 us; speedup 1.0000x reference)
//
#include <hip/hip_runtime.h>
#include <math.h>

// Problem: x (B=2, C=64, T=16, H=128, W=128) fp32; w (1,2,7,7,7) fp32.
// out = sigmoid(conv3d(concat[max_c(x), mean_c(x)], w, pad=3)) * x
//
// R16 structure (resubmitted R23 — rounds 14-20 all hit GPU-acquisition
// timeouts; this source has never been benched):
// R14 (8x128 wave-linear strips) with ONE change: all stream stores are
// PLAIN (write-back through L2) instead of non-temporal.
// Evidence ledger:
//   - ~170 us of the timed region is fixed harness fills (R5 coop probe).
//   - R9: conv ~14 us; stream ~60 us is the target; more blocks don't help.
//     FETCH=80 MiB: x got evicted from L3 DESPITE nt stores -> nt gives the
//     penalty without the benefit.
//   - R12: load/store chunking + sched_barrier = flat -> ordering exonerated.
//   - R14: wave-linear retile = flat -> coalescing exonerated.
//   - fillBufferAligned: plain stores, wave-linear, 6.7 TB/s. Our stream:
//     same shape, same occupancy, nt stores, ~1-2 TB/s write rate. nt on
//     CDNA (sc0/sc1/nt) bypasses L2 write-back aggregation -> HBM bursts at
//     write-through pace. Plain stores let L2 coalesce like the fill.
//   K1 pool:  x (128 MiB) -> pmax|pavg (4 MiB)   [6.5 TB/s, ~21 us]
//   K2:       block = (b, t, 8-row strip); wave = 2 full rows = 1 KiB
//             contiguous accesses; conv per thread unchanged; plain stores.

#define NP (2 * 16 * 128 * 128) // 524288 pooled points per channel
#define SMH 14                  // halo rows per plane (8 + 6)
#define SMW 134                 // halo cols (128 + 6)
#define SMSTRIDE 136            // row stride (16B-aligned: 136*4 = 544 = 34*16)
#define SMCH (SMH * SMSTRIDE)   // 1904 floats per channel plane

typedef float vfloat4 __attribute__((ext_vector_type(4)));
typedef float vfloat2 __attribute__((ext_vector_type(2)));

// ---------------- Kernel 1: channel max + mean pool (float4) ----------------
__global__ __launch_bounds__(256) void pool_kernel(const float* __restrict__ x,
                                                   float* __restrict__ pmax,
                                                   float* __restrict__ pavg) {
    int j = blockIdx.x * 256 + threadIdx.x; // float4 index in pooled space, [0, 131072)
    int b = j >> 16;                        // 65536 float4 per batch in pooled space
    int rest = j & 65535;
    const float4* x4 = (const float4*)x;
    int base = (b << 22) | rest;            // float4 index into x for c=0

    float4 v = x4[base];
    float4 vmax = v;
    float4 vsum = v;
#pragma unroll 8
    for (int c = 1; c < 64; ++c) {
        float4 u = x4[base + (c << 16)];
        vmax.x = fmaxf(vmax.x, u.x);
        vmax.y = fmaxf(vmax.y, u.y);
        vmax.z = fmaxf(vmax.z, u.z);
        vmax.w = fmaxf(vmax.w, u.w);
        vsum.x += u.x; vsum.y += u.y; vsum.z += u.z; vsum.w += u.w;
    }
    const float s = 1.0f / 64.0f;
    float4 vavg; vavg.x = vsum.x * s; vavg.y = vsum.y * s; vavg.z = vsum.z * s; vavg.w = vsum.w * s;
    ((float4*)pmax)[j] = vmax;
    ((float4*)pavg)[j] = vavg;
}

// ---- Kernel 2: 7x7x7 conv (2ch) + sigmoid + multiply, 8x128 strip tiles ----
// 512 blocks: bid = [b(1) | t(4) | strip(4)]. Block covers rows
// th0..th0+7, all 128 w. Thread: ty = tid>>5 (row), tx = tid&31 (float4 col),
// owns 4 consecutive w-pixels. Wave = rows {2w, 2w+1} full-width = 1 KiB
// contiguous global accesses.
__global__ __launch_bounds__(256) void conv_mul_kernel(const float* __restrict__ pooled, // pmax | pavg contiguous
                                                       const float* __restrict__ wgt,    // (1,2,7,7,7)
                                                       const float* __restrict__ x,
                                                       float* __restrict__ out) {
    __shared__ __align__(16) float sm[2 * SMCH]; // 15232 B

    int bid = blockIdx.x;
    int strip = bid & 15;
    int t = (bid >> 4) & 15;
    int b = bid >> 8;
    int th0 = strip << 3;

    int tid = threadIdx.x;
    int ty = tid >> 5;        // 0..7 row within strip
    int tx = tid & 31;        // float4 col 0..31

    // float4 index: b*2^22 + c*2^16 + t*2^12 + h*2^5 + w/4
    int base4 = (b << 22) + (t << 12) + ((th0 + ty) << 5) + tx;
    int cs = bid & 63; // per-block channel stagger
    const vfloat4* x4 = (const vfloat4*)x;
    vfloat4* o4 = (vfloat4*)out;

    // Prefetch chunk 0 (16 staggered channels): loads fly during the conv
    // phase; data parks in VGPRs until the streaming phase.
    vfloat4 pre[16];
#pragma unroll
    for (int k = 0; k < 16; ++k)
        pre[k] = x4[base4 + (((cs + k) & 63) << 16)];

    float acc0 = 0.f, acc1 = 0.f, acc2 = 0.f, acc3 = 0.f;

    for (int dz = 0; dz < 7; ++dz) {
        int tsrc = t + dz - 3;
        if (tsrc < 0 || tsrc >= 16) continue; // block-uniform: barriers stay uniform

        __syncthreads(); // protect LDS from previous plane's readers
        // Fixed-trip staging: 15 predicated iterations (2*1904 = 3808 slots),
        // all loads independent. sm is written linearly (sm[i]); cols >= 134
        // are padding and get 0.
#pragma unroll
        for (int r = 0; r < 15; ++r) {
            int i = tid + (r << 8);
            int ch = i / SMCH;
            int rem = i - ch * SMCH;
            int y = rem / SMSTRIDE;
            int xx = rem - y * SMSTRIDE;
            int gh = th0 + y - 3;
            int gw = xx - 3;
            float val = 0.f;
            if (i < 2 * SMCH && xx < SMW && (unsigned)gh < 128u && (unsigned)gw < 128u)
                val = pooled[ch * NP + (((b << 4) + tsrc) << 14) + (gh << 7) + gw];
            if (i < 2 * SMCH)
                sm[i] = val;
        }
        __syncthreads();

        const float* wdz = wgt + dz * 49;
#pragma unroll
        for (int ch = 0; ch < 2; ++ch) {
#pragma unroll
            for (int dy = 0; dy < 7; ++dy) {
                // Output pixels w = tx*4+j (j=0..3); halo col xx = w + dx.
                // Row base: halo offset tx*4, 16B-aligned (stride 544B).
                const float* rp = &sm[ch * SMCH + (ty + dy) * SMSTRIDE + (tx << 2)];
                vfloat4 r0 = *(const vfloat4*)rp;        // xx tx*4+0..3
                vfloat4 r1 = *(const vfloat4*)(rp + 4);  // +4..7
                vfloat2 r2 = *(const vfloat2*)(rp + 8);  // +8..9
                float row[10] = {r0.x, r0.y, r0.z, r0.w,
                                 r1.x, r1.y, r1.z, r1.w,
                                 r2.x, r2.y};
                const float* wr = wdz + ch * 343 + dy * 7;
#pragma unroll
                for (int dx = 0; dx < 7; ++dx) {
                    float wv = wr[dx];
                    acc0 = fmaf(wv, row[dx + 0], acc0);
                    acc1 = fmaf(wv, row[dx + 1], acc1);
                    acc2 = fmaf(wv, row[dx + 2], acc2);
                    acc3 = fmaf(wv, row[dx + 3], acc3);
                }
            }
        }
    }

    vfloat4 av;
    av.x = 1.f / (1.f + __expf(-acc0));
    av.y = 1.f / (1.f + __expf(-acc1));
    av.z = 1.f / (1.f + __expf(-acc2));
    av.w = 1.f / (1.f + __expf(-acc3));

    // Stream phase, chunked: {16 loads} -> {16 mul+store} per chunk.
    // PLAIN stores (write-back through L2, like the 6.7 TB/s fill kernel);
    // nt stores measured ~1-2 TB/s and failed to keep x L3-resident anyway.
#pragma unroll
    for (int k = 0; k < 16; ++k) {
        int idx = base4 + (((cs + k) & 63) << 16);
        o4[idx] = pre[k] * av;
    }
    for (int cch = 1; cch < 4; ++cch) { // not unrolled: buf reused, VGPR capped
        vfloat4 buf[16];
#pragma unroll
        for (int k = 0; k < 16; ++k)
            buf[k] = x4[base4 + (((cs + (cch << 4) + k) & 63) << 16)];
        __builtin_amdgcn_sched_barrier(0); // pin: all 16 loads issue before stores
#pragma unroll
        for (int k = 0; k < 16; ++k) {
            int idx = base4 + (((cs + (cch << 4) + k) & 63) << 16);
            o4[idx] = buf[k] * av;
        }
    }
}

extern "C" void kernel_launch(void* const* d_in, const int* in_sizes, int n_in,
                              void* d_out, int out_size, void* d_ws, size_t ws_size,
                              hipStream_t stream) {
    const float* x = (const float*)d_in[0];
    const float* w = (const float*)d_in[1];
    float* out = (float*)d_out;
    float* ws = (float*)d_ws;

    float* pmax = ws;       // NP floats
    float* pavg = ws + NP;  // NP floats (must follow pmax: conv indexes ch*NP)

    pool_kernel<<<NP / 4 / 256, 256, 0, stream>>>(x, pmax, pavg);
    conv_mul_kernel<<<2 * 16 * 16, 256, 0, stream>>>(pmax, w, x, out);
}